// Round 4
// baseline (642.555 us; speedup 1.0000x reference)
//
#include <hip/hip_runtime.h>

// Spatialize via MFMA, v2: A (Toeplitz of h) comes straight from a precomputed
// global table of REVERSED bf16 h, stored as 8 alignment-shifted copies so every
// lane's 8-elem fragment is a 16B-aligned global_load_dwordx4 (L1-resident:
// the live window slides 64 B per chunk). B (x) stays in LDS ping-pong.
// Wave tile: 64 times x 64 batches x 2 ch -> 32 MFMA per 4 LDS reads per chunk.
// Numerics bit-identical to round-3 kernel (same f2bf, chunk order, MFMA seq).

#define K_TAPS  10000
#define T_LEN   150000
#define OUT_T0  12500
#define OUT_T1  137500
#define OUT_LEN 125000
#define BATCH   64

#define TM    256                 // output times per block (4 waves x 64)
#define KC    32                  // K per chunk
#define D0    10016               // t0 - p_start (mult of 32, >= 9999+... )
#define NC    321                 // (D0+TM)/KC
#define NMAX  (D0 + TM - 1)       // 10271
#define NTAB  10528               // elems per copy (max s = 10519, +8, 16B mult)
#define CS_BYTES  (NTAB * 2)      // 21056 (16B multiple)
#define CH_STRIDE (8 * CS_BYTES)  // 168448
#define TAB_BYTES (2 * CH_STRIDE) // 336896  (d_ws must be >= this)

#define XCOLS 40                  // 32 + 8 pad: 80B pitch, uniform bank spread

typedef short  bf16x8 __attribute__((ext_vector_type(8)));
typedef float  f32x4  __attribute__((ext_vector_type(4)));

__device__ __forceinline__ unsigned f2bf(float f) {
    unsigned u = __builtin_bit_cast(unsigned, f);
    return (u + 0x7FFFu + ((u >> 16) & 1u)) >> 16;   // RNE, same as round 3
}

// tab[ch][rho][m] = hpad[NMAX - (m + rho)]  (zero outside [0,K_TAPS))
__global__ __launch_bounds__(256) void build_tab(
    const float* __restrict__ ir, ushort* __restrict__ tab)
{
    const int m = blockIdx.x * 256 + threadIdx.x;
    if (m >= NTAB) return;
    const int y   = blockIdx.y;        // 0..15
    const int ch  = y >> 3;
    const int rho = y & 7;
    const int d   = NMAX - m - rho;
    const float v = (d >= 0 && d < K_TAPS) ? ir[2 * d + ch] : 0.f;
    tab[(size_t)ch * (8 * NTAB) + (size_t)rho * NTAB + m] = (ushort)f2bf(v);
}

__global__ __launch_bounds__(256, 2) void spatialize_mfma2(
    const float* __restrict__ x, const ushort* __restrict__ tab,
    float* __restrict__ out)
{
    __shared__ ushort xb[2][BATCH][XCOLS];   // 10240 B

    const int tid  = threadIdx.x;
    const int lane = tid & 63;
    const int wm   = tid >> 6;               // 4 waves, all along M (time)
    const int lrow = lane & 15;
    const int koff = (lane >> 4) * 8;        // k element offset of fragment

    // bijective XCD-chunked swizzle (nwg % 8 != 0 safe)
    const int nwg = gridDim.x;
    const int q8 = nwg >> 3, r8 = nwg & 7;
    const int xcd = blockIdx.x & 7, loc = blockIdx.x >> 3;
    const int tile = (xcd < r8 ? xcd * (q8 + 1) : r8 * (q8 + 1) + (xcd - r8) * q8) + loc;

    const int t0      = OUT_T0 + tile * TM;
    const int p_start = t0 - D0;             // >= 2484, %4==0

    // ---- A addressing: s_eff = NMAX - Di - m0 - lrow + koff, Di = D0 - 32i,
    // m0 = wm*64 + mt*16. rho = s&7 invariant (all strides = 0 mod 8).
    // byte(s) = (s&7)*CS_BYTES + (s>>3)*16 ; per chunk += 64 ; per mt -= 32.
    const int s0 = NMAX - D0 - wm * 64 - lrow + koff;   // chunk 0, mt 0 (>=48)
    int aoff = (s0 & 7) * CS_BYTES + ((s0 >> 3) << 4);
    const char* tA0 = (const char*)tab;                 // channel L
    const char* tA1 = (const char*)tab + CH_STRIDE;     // channel R

    // ---- x staging mapping: 256 thr -> 64 rows x 4 quads of 8 elems
    const int sb = tid >> 2;
    const int sg = tid & 3;
    const float* xrow = x + (size_t)sb * T_LEN + p_start + sg * 8;

    // stage chunk 0
    {
        const float4 v0 = *(const float4*)(xrow);
        const float4 v1 = *(const float4*)(xrow + 4);
        uint4 w;
        w.x = f2bf(v0.x) | (f2bf(v0.y) << 16);
        w.y = f2bf(v0.z) | (f2bf(v0.w) << 16);
        w.z = f2bf(v1.x) | (f2bf(v1.y) << 16);
        w.w = f2bf(v1.z) | (f2bf(v1.w) << 16);
        *(uint4*)&xb[0][sb][sg * 8] = w;
    }
    __syncthreads();

    f32x4 acc[4][4][2];   // [mt][nt][ch] = 128 VGPR
#pragma unroll
    for (int mt = 0; mt < 4; ++mt)
#pragma unroll
        for (int nt = 0; nt < 4; ++nt)
#pragma unroll
            for (int ch = 0; ch < 2; ++ch)
                acc[mt][nt][ch] = (f32x4){0.f, 0.f, 0.f, 0.f};

    for (int i = 0; i < NC; ++i) {
        const int  cur  = i & 1;
        const bool more = (i + 1 < NC);

        // (1) issue next-chunk x loads early (latency under MFMA)
        float4 v0, v1;
        if (more) {
            const float* xp = xrow + (i + 1) * KC;
            v0 = *(const float4*)(xp);
            v1 = *(const float4*)(xp + 4);
        }

        // (2) A fragments straight from global (L1-resident sliding window)
        bf16x8 af0[4], af1[4];
#pragma unroll
        for (int mt = 0; mt < 4; ++mt) {
            af0[mt] = *(const bf16x8*)(tA0 + (aoff - 32 * mt));
            af1[mt] = *(const bf16x8*)(tA1 + (aoff - 32 * mt));
        }
        // (3) B fragments from LDS
        bf16x8 bfr[4];
#pragma unroll
        for (int nt = 0; nt < 4; ++nt)
            bfr[nt] = *(const bf16x8*)&xb[cur][nt * 16 + lrow][koff];

        // (4) 32 MFMAs
#pragma unroll
        for (int mt = 0; mt < 4; ++mt)
#pragma unroll
            for (int nt = 0; nt < 4; ++nt) {
                acc[mt][nt][0] = __builtin_amdgcn_mfma_f32_16x16x32_bf16(
                    af0[mt], bfr[nt], acc[mt][nt][0], 0, 0, 0);
                acc[mt][nt][1] = __builtin_amdgcn_mfma_f32_16x16x32_bf16(
                    af1[mt], bfr[nt], acc[mt][nt][1], 0, 0, 0);
            }

        // (5) write next-chunk x to the other buffer
        if (more) {
            uint4 w;
            w.x = f2bf(v0.x) | (f2bf(v0.y) << 16);
            w.y = f2bf(v0.z) | (f2bf(v0.w) << 16);
            w.z = f2bf(v1.x) | (f2bf(v1.y) << 16);
            w.w = f2bf(v1.z) | (f2bf(v1.w) << 16);
            *(uint4*)&xb[cur ^ 1][sb][sg * 8] = w;
        }
        __syncthreads();
        aoff += 64;
    }

    // ---- epilogue: D frag col=lane&15 -> batch, row=(lane>>4)*4+reg -> time
    const int r4 = (lane >> 4) * 4;
#pragma unroll
    for (int mt = 0; mt < 4; ++mt) {
        const int t4 = t0 + wm * 64 + mt * 16 + r4;
        if (t4 < OUT_T1) {   // OUT_T1 % 4 == 0 -> whole float4 in or out
#pragma unroll
            for (int nt = 0; nt < 4; ++nt) {
                const int b = nt * 16 + lrow;
#pragma unroll
                for (int ch = 0; ch < 2; ++ch) {
                    const f32x4 a = acc[mt][nt][ch];
                    *(float4*)&out[(size_t)b * (2 * OUT_LEN) +
                                   (size_t)ch * OUT_LEN + (t4 - OUT_T0)] =
                        make_float4(a[0], a[1], a[2], a[3]);
                }
            }
        }
    }
}

extern "C" void kernel_launch(void* const* d_in, const int* in_sizes, int n_in,
                              void* d_out, int out_size, void* d_ws, size_t ws_size,
                              hipStream_t stream)
{
    (void)in_sizes; (void)n_in; (void)out_size; (void)ws_size; // needs >= 337 KB
    const float* x  = (const float*)d_in[0];
    const float* ir = (const float*)d_in[1];
    float* out      = (float*)d_out;
    ushort* tab     = (ushort*)d_ws;

    // build reversed-h table (8 shifted copies x 2 ch), every call (ws re-poisoned)
    dim3 gt((NTAB + 255) / 256, 16);
    hipLaunchKernelGGL(build_tab, gt, dim3(256), 0, stream, ir, tab);

    dim3 grid((OUT_LEN + TM - 1) / TM);   // 489
    hipLaunchKernelGGL(spatialize_mfma2, grid, dim3(256), 0, stream, x, tab, out);
}